// Round 17
// baseline (375.666 us; speedup 1.0000x reference)
//
#include <hip/hip_runtime.h>

typedef unsigned short u16;
typedef unsigned char u8;
typedef __attribute__((ext_vector_type(8))) short short8;
typedef __attribute__((ext_vector_type(4))) float f32x4;

#define Bn 4096
#define Vn 20
#define Dn 768
#define Mn (Bn * Vn)   // 81920 rows
#define Nn (2 * Dn)    // 1536 packed m1/m2 columns

#define BM 256
#define BNt 256            // Wt rows per block tile (= 128 output e-columns)
#define NTILES (Nn / BNt)  // 6 N-tiles
#define GRID ((Mn / BM) * NTILES)   // 320 * 6 = 1920, %8 == 0
#define PANEL (256 * Dn)   // bytes per 256-row fp8 panel (196608)

#define SCL 32.0f          // fp8 pre-scale for X and W
#define ISCL2 (1.0f / 1024.0f)

typedef __attribute__((address_space(1))) void GV;
typedef __attribute__((address_space(3))) void LV;

__device__ __forceinline__ u16 f2bf(float f) {
  union { float f; unsigned u; } v; v.f = f;
  unsigned r = v.u + 0x7FFFu + ((v.u >> 16) & 1u);  // round-to-nearest-even
  return (u16)(r >> 16);
}
__device__ __forceinline__ float bf2f(u16 x) {
  union { unsigned u; float f; } v; v.u = ((unsigned)x) << 16; return v.f;
}

// Tiled fp8 layout (GLOBAL == LDS, linear copy): a 256-row x 32-byte K-slice
// (8192 B) is stored as [4 k-planes(8B)][128 row-pairs][2 rows][8 B]:
//   byte(q, kb) = (kb>>3)*2048 + (q>>1)*16 + (q&1)*8 + (kb&7)
// Fragment read (lane lo,hi: row q=R0+lo, k-bytes [hi*8,+8)):
//   addr = hi*2048 + (R0/2 + (lo>>1))*16 + (lo&1)*8
// -> each 16-lane b64 pass covers 128 CONTIGUOUS bytes = 32 banks, 0 conflicts.

// ---------------- kernel 1: row softmax -> fp8 X (x32 scale, tiled) ---------
__global__ __launch_bounds__(192) void softmax_k(const float* __restrict__ vf,
                                                 u8* __restrict__ X8) {
  size_t row = blockIdx.x;
  const float4* p = (const float4*)(vf + row * Dn);
  int t = threadIdx.x;
  float4 v = p[t];
  float mx = fmaxf(fmaxf(v.x, v.y), fmaxf(v.z, v.w));
  #pragma unroll
  for (int off = 32; off; off >>= 1) mx = fmaxf(mx, __shfl_xor(mx, off));
  __shared__ float rr[3];
  __shared__ float rs[3];
  int wv = t >> 6, ln = t & 63;
  if (!ln) rr[wv] = mx;
  __syncthreads();
  mx = fmaxf(fmaxf(rr[0], rr[1]), rr[2]);
  float e0 = __expf(v.x - mx), e1 = __expf(v.y - mx);
  float e2 = __expf(v.z - mx), e3 = __expf(v.w - mx);
  float s = e0 + e1 + e2 + e3;
  #pragma unroll
  for (int off = 32; off; off >>= 1) s += __shfl_xor(s, off);
  if (!ln) rs[wv] = s;
  __syncthreads();
  float inv = SCL / (rs[0] + rs[1] + rs[2]);
  unsigned pk = 0;
  pk = __builtin_amdgcn_cvt_pk_fp8_f32(e0 * inv, e1 * inv, pk, false);
  pk = __builtin_amdgcn_cvt_pk_fp8_f32(e2 * inv, e3 * inv, pk, true);
  // thread t covers k-bytes [t*4, t*4+4): ks=t>>3, plane=(t>>1)&3, b=(t&1)*4
  const int q = (int)(row & 255);
  u8* dst = X8 + (row >> 8) * PANEL + (size_t)(t >> 3) * 8192
            + ((t >> 1) & 3) * 2048 + (q >> 1) * 16 + (q & 1) * 8 + (t & 1) * 4;
  *(unsigned*)dst = pk;
}

// ---- kernel 2: pack W1/W2 block-of-32 interleaved, fp8 x32, tiled ----------
__global__ __launch_bounds__(256) void build_wt_k(const float* __restrict__ W1,
                                                  const float* __restrict__ W2,
                                                  u8* __restrict__ Wt8) {
  int idx = blockIdx.x * 256 + threadIdx.x;        // over 768 * 192
  if (idx >= Dn * (Dn / 4)) return;
  int j = idx / (Dn / 4), d4 = (idx - j * (Dn / 4)) * 4;
  int b = j >> 5, c = j & 31;
  float4 a = *(const float4*)(W1 + (size_t)j * Dn + d4);
  float4 e = *(const float4*)(W2 + (size_t)j * Dn + d4);
  unsigned p1 = 0, p2 = 0;
  p1 = __builtin_amdgcn_cvt_pk_fp8_f32(a.x * SCL, a.y * SCL, p1, false);
  p1 = __builtin_amdgcn_cvt_pk_fp8_f32(a.z * SCL, a.w * SCL, p1, true);
  p2 = __builtin_amdgcn_cvt_pk_fp8_f32(e.x * SCL, e.y * SCL, p2, false);
  p2 = __builtin_amdgcn_cvt_pk_fp8_f32(e.z * SCL, e.w * SCL, p2, true);
  const int slice = d4 >> 5, plane = (d4 >> 3) & 3, bb = d4 & 7;
  const int j1 = b * 64 + c, j2 = b * 64 + 32 + c;
  const int q1 = j1 & 255, q2 = j2 & 255;
  *(unsigned*)(Wt8 + (size_t)(j1 >> 8) * PANEL + (size_t)slice * 8192
               + plane * 2048 + (q1 >> 1) * 16 + (q1 & 1) * 8 + bb) = p1;
  *(unsigned*)(Wt8 + (size_t)(j2 >> 8) * PANEL + (size_t)slice * 8192
               + plane * 2048 + (q2 >> 1) * 16 + (q2 & 1) * 8 + bb) = p2;
}

// -------- kernel 3: fp8 GEMM (8-phase, conflict-free tiled LDS) + conv ------
// Same schedule/barrier/vmcnt ledger as the verified R16 kernel; only the
// byte placement changed (tiled global == LDS, pure linear staging copy).
// Slices: K-tile T (0..11), K-half kh -> slice 2T+kh (8192 B each).
__global__ __launch_bounds__(512, 2) void gemm_fuse_k(
    const u8* __restrict__ X8, const u8* __restrict__ Wt8,
    const float* __restrict__ b1, const float* __restrict__ b2,
    const float* __restrict__ text, float* __restrict__ out,
    u16* __restrict__ seam,
    const float* __restrict__ cw1, const float* __restrict__ cb1,
    const float* __restrict__ cw2, const float* __restrict__ cb2) {
  __shared__ __align__(16) u16 smem[65536];   // 128 KiB (K-loop uses 64 KiB)
  u8* smem8 = (u8*)smem;

  const int h = blockIdx.x;                      // GRID = 1920 blocks, %8==0
  const int lin = (h & 7) * (GRID / 8) + (h >> 3);
  const int by = lin / NTILES, bx = lin - by * NTILES;
  const int brow = by * BM;

  const int t = threadIdx.x, w = t >> 6, l = t & 63;
  const int lo = l & 15, hi = l >> 4;
  const int wrr = w >> 2, wcc = w & 3;

  int offA[8], offB[4];
  #pragma unroll
  for (int m = 0; m < 8; ++m)
    offA[m] = hi * 2048 + (wrr * 64 + m * 8 + (lo >> 1)) * 16 + (lo & 1) * 8;
  #pragma unroll
  for (int n = 0; n < 4; ++n)
    offB[n] = hi * 2048 + (wcc * 32 + n * 8 + (lo >> 1)) * 16 + (lo & 1) * 8;

  // staging: tiled global slice is byte-identical to the LDS region
  const u8* gAp = X8 + (size_t)by * PANEL + t * 16;
  const u8* gBp = Wt8 + (size_t)bx * PANEL + t * 16;

#define STG_A(DST, SL) __builtin_amdgcn_global_load_lds( \
    (GV*)(gAp + (size_t)(SL) * 8192), (LV*)(smem8 + (DST) + w * 1024), 16, 0, 0)
#define STG_B(DST, SL) __builtin_amdgcn_global_load_lds( \
    (GV*)(gBp + (size_t)(SL) * 8192), (LV*)(smem8 + (DST) + w * 1024), 16, 0, 0)

  // prologue: T0Kh0, T1Kh0, T0Kh1, T1Kh1 (8 loads)
  STG_A(0, 0);              STG_B(16384, 0);          // T0 Kh0 -> slot0
  STG_A(32768, 2);          STG_B(49152, 2);          // T1 Kh0 -> slot1
  STG_A(8192, 1);           STG_B(24576, 1);          // T0 Kh1
  STG_A(40960, 3);          STG_B(57344, 3);          // T1 Kh1
  asm volatile("s_waitcnt vmcnt(6)" ::: "memory");    // T0-Kh0 resident
  __builtin_amdgcn_s_barrier();

  f32x4 acc[8][4] = {};
  long af[8], bb0, bb1;

#define PH(SB, KH, NH, NEWA, STG, VM) do {                                     \
    if (NEWA) { _Pragma("unroll") for (int m = 0; m < 8; ++m)                  \
      af[m] = *(const long*)(smem8 + (SB) + (KH) * 8192 + offA[m]); }          \
    bb0 = *(const long*)(smem8 + (SB) + 16384 + (KH) * 8192 + offB[(NH)*2]);   \
    bb1 = *(const long*)(smem8 + (SB) + 16384 + (KH) * 8192 + offB[(NH)*2+1]); \
    STG;                                                                       \
    __builtin_amdgcn_s_barrier();                                              \
    asm volatile("s_waitcnt lgkmcnt(0)" ::: "memory");                         \
    __builtin_amdgcn_sched_barrier(0);                                         \
    __builtin_amdgcn_s_setprio(1);                                             \
    _Pragma("unroll") for (int m = 0; m < 8; ++m) {                            \
      acc[m][(NH)*2]   = __builtin_amdgcn_mfma_f32_16x16x32_fp8_fp8(af[m], bb0, acc[m][(NH)*2],   0, 0, 0); \
      acc[m][(NH)*2+1] = __builtin_amdgcn_mfma_f32_16x16x32_fp8_fp8(af[m], bb1, acc[m][(NH)*2+1], 0, 0, 0); \
    }                                                                          \
    __builtin_amdgcn_s_setprio(0);                                             \
    VM;                                                                        \
    __builtin_amdgcn_s_barrier();                                              \
  } while (0)

#define VM2 asm volatile("s_waitcnt vmcnt(2)" ::: "memory")
#define VM0 asm volatile("s_waitcnt vmcnt(0)" ::: "memory")

  #pragma unroll
  for (int i = 0; i < 6; ++i) {
    const int sa = 2 * (2 * i + 1);    // slices of tile staged into slot1
    const int sb = 2 * (2 * i + 2);    // slices of tile staged into slot0
    PH(0, 0, 0, true,  if (i >= 1) STG_A(32768, sa),     ;  );
    PH(0, 0, 1, false, if (i >= 1) STG_B(49152, sa),     VM2);
    PH(0, 1, 0, true,  if (i >= 1) STG_A(40960, sa + 1), ;  );
    PH(0, 1, 1, false, if (i >= 1) STG_B(57344, sa + 1), VM2);
    PH(32768, 0, 0, true,  if (i <= 4) STG_A(0, sb),         ;  );
    PH(32768, 0, 1, false, if (i <= 4) STG_B(16384, sb),     if (i == 5) { VM0; } else { VM2; });
    PH(32768, 1, 0, true,  if (i <= 4) STG_A(8192, sb + 1),  ;  );
    PH(32768, 1, 1, false, if (i <= 4) STG_B(24576, sb + 1), if (i <= 4) { VM2; });
  }
#undef PH
#undef VM2
#undef VM0
#undef STG_A
#undef STG_B

  // ======================= fused-conv epilogue ==============================
  // vmcnt==0 here (i=5 P6 drained; P7/P8 stage nothing) -> smem reusable.
  const float w10 = cw1[0], w11 = cw1[1], w12 = cw1[2], c1b = cb1[0];
  const float w20 = cw2[0], w21 = cw2[1], w22 = cw2[2], c2b = cb2[0];

  u16* fsm = smem;           // fused [c][r]: idx = c*256 + (r ^ ((c&31)<<3))
  u16* tsm = smem + 32768;   // tmp, same layout

  // ---- E1: fused -> LDS bf16 (+ seam store for cols 0-3,124-127) ----
  #pragma unroll
  for (int n = 0; n < 2; ++n) {
    const int cl = wcc * 32 + n * 16 + lo;       // local col 0..127
    const int e  = bx * 128 + cl;
    const float B1 = b1[e], B2 = b2[e];
    #pragma unroll
    for (int m = 0; m < 8; ++m) {
      const int rl = wrr * 128 + m * 16 + hi * 4;
      uint2 pk;
      u16* pku = (u16*)&pk;
      #pragma unroll
      for (int r = 0; r < 4; ++r) {
        const int gr = brow + rl + r;
        const float v1 = acc[m][n][r] * ISCL2 + B1;
        const float v2 = acc[m][n + 2][r] * ISCL2 + B2;
        const float tf = text[(size_t)(gr / Vn) * Dn + e];
        pku[r] = f2bf(fmaxf(tf * v1 + v2, 0.0f));
      }
      *(uint2*)(fsm + cl * 256 + (rl ^ ((cl & 31) << 3))) = pk;
      const int sidx = (cl < 4) ? cl : ((cl >= 124) ? cl - 120 : -1);
      if (sidx >= 0)
        *(uint2*)(seam + ((size_t)(by * 6 + bx) * 8 + sidx) * 256 + rl) = pk;
    }
  }
  __syncthreads();

  // ---- E2: tmp = relu(conv1(fused)), per-thread col; own col kept in regs --
  const int cl = t & 127, rb = t >> 7;
  const int cL = cl ? cl - 1 : 0, cR = (cl < 127) ? cl + 1 : 127;
  short8 tC[8];
  #pragma unroll
  for (int j = 0; j < 8; ++j) {
    const int R = rb * 64 + j * 8;
    short8 sL = *(const short8*)(fsm + cL * 256 + (R ^ ((cL & 31) << 3)));
    short8 sC = *(const short8*)(fsm + cl * 256 + (R ^ ((cl & 31) << 3)));
    short8 sR = *(const short8*)(fsm + cR * 256 + (R ^ ((cR & 31) << 3)));
    short8 o;
    #pragma unroll
    for (int k = 0; k < 8; ++k) {
      float a = bf2f((u16)sL[k]), b = bf2f((u16)sC[k]), c = bf2f((u16)sR[k]);
      float v = fmaxf(fmaf(w10, a, fmaf(w11, b, fmaf(w12, c, c1b))), 0.0f);
      o[k] = (short)f2bf(v);
    }
    *(short8*)(tsm + cl * 256 + (R ^ ((cl & 31) << 3))) = o;
    tC[j] = o;
  }
  __syncthreads();

  // ---- E3: out = conv2(tmp), store interior cols 2..125 ----
  const bool wr_ok = (cl >= 2 && cl <= 125);
  #pragma unroll
  for (int j = 0; j < 8; ++j) {
    const int R = rb * 64 + j * 8;
    short8 tL = *(const short8*)(tsm + cL * 256 + (R ^ ((cL & 31) << 3)));
    short8 tR = *(const short8*)(tsm + cR * 256 + (R ^ ((cR & 31) << 3)));
    #pragma unroll
    for (int k = 0; k < 8; ++k) {
      float v = fmaf(w20, bf2f((u16)tL[k]),
                fmaf(w21, bf2f((u16)tC[j][k]),
                fmaf(w22, bf2f((u16)tR[k]), c2b)));
      if (wr_ok)
        out[(size_t)(brow + R + k) * Dn + bx * 128 + cl] = v;
    }
  }
}

// ------- kernel 4: seam cleanup — out cols {E0,E0+1,E0+126,E0+127} ---------
// Zero-pad semantics: conv2's pad gives tmp(-1)=tmp(768)=0 (NOT conv1 of
// zeros); conv1's pad gives fused(-1)=fused(768)=0 inside tmp(0)/tmp(767).
__global__ __launch_bounds__(256) void seam_k(const u16* __restrict__ seam,
                                              float* __restrict__ out,
                                              const float* __restrict__ cw1,
                                              const float* __restrict__ cb1,
                                              const float* __restrict__ cw2,
                                              const float* __restrict__ cb2) {
  const int bid = blockIdx.x;          // by*6+bx
  const int by = bid / 6, bx = bid - by * 6;
  const int r = threadIdx.x;
  const float w10 = cw1[0], w11 = cw1[1], w12 = cw1[2], c1b = cb1[0];
  const float w20 = cw2[0], w21 = cw2[1], w22 = cw2[2], c2b = cb2[0];
  #define SM(B, I) bf2f(seam[((size_t)(B) * 8 + (I)) * 256 + r])
  float fm2 = 0.f, fm1 = 0.f, fR0 = 0.f, fR1 = 0.f;
  if (bx > 0) { fm2 = SM(bid - 1, 6); fm1 = SM(bid - 1, 7); }
  if (bx < 5) { fR0 = SM(bid + 1, 0); fR1 = SM(bid + 1, 1); }
  const float f0 = SM(bid, 0), f1 = SM(bid, 1), f2 = SM(bid, 2), f3 = SM(bid, 3);
  const float f124 = SM(bid, 4), f125 = SM(bid, 5), f126 = SM(bid, 6), f127 = SM(bid, 7);
  #undef SM
  #define C1(a, b, c) fmaxf(fmaf(w10, (a), fmaf(w11, (b), fmaf(w12, (c), c1b))), 0.0f)
  const float tm1  = (bx > 0) ? C1(fm2, fm1, f0) : 0.0f;   // tmp(-1)=0 at edge
  const float t0   = C1(fm1, f0, f1);
  const float t1   = C1(f0, f1, f2);
  const float t2   = C1(f1, f2, f3);
  const float t125 = C1(f124, f125, f126);
  const float t126 = C1(f125, f126, f127);
  const float t127 = C1(f126, f127, fR0);
  const float t128 = (bx < 5) ? C1(f127, fR0, fR1) : 0.0f;  // tmp(768)=0 at edge
  #undef C1
  const size_t go = (size_t)(by * 256 + r) * Dn + bx * 128;
  out[go + 0]   = fmaf(w20, tm1,  fmaf(w21, t0,   fmaf(w22, t1,   c2b)));
  out[go + 1]   = fmaf(w20, t0,   fmaf(w21, t1,   fmaf(w22, t2,   c2b)));
  out[go + 126] = fmaf(w20, t125, fmaf(w21, t126, fmaf(w22, t127, c2b)));
  out[go + 127] = fmaf(w20, t126, fmaf(w21, t127, fmaf(w22, t128, c2b)));
}

extern "C" void kernel_launch(void* const* d_in, const int* in_sizes, int n_in,
                              void* d_out, int out_size, void* d_ws, size_t ws_size,
                              hipStream_t stream) {
  const float* text = (const float*)d_in[0];
  const float* vf   = (const float*)d_in[1];
  const float* W1   = (const float*)d_in[2];
  const float* b1   = (const float*)d_in[3];
  const float* W2   = (const float*)d_in[4];
  const float* b2   = (const float*)d_in[5];
  const float* cw1  = (const float*)d_in[6];
  const float* cb1  = (const float*)d_in[7];
  const float* cw2  = (const float*)d_in[8];
  const float* cb2  = (const float*)d_in[9];
  float* out = (float*)d_out;

  u8*  X8   = (u8*)d_ws;                                   // [320 panels] tiled fp8
  u8*  Wt8  = X8 + (size_t)Mn * Dn;                        // [6 panels] tiled fp8
  u16* seam = (u16*)(Wt8 + (size_t)Nn * Dn);               // [1920][8][256] bf16

  softmax_k<<<Mn, 192, 0, stream>>>(vf, X8);
  build_wt_k<<<(Dn * (Dn / 4) + 255) / 256, 256, 0, stream>>>(W1, W2, Wt8);
  gemm_fuse_k<<<GRID, 512, 0, stream>>>(X8, Wt8, b1, b2, text, out, seam,
                                        cw1, cb1, cw2, cb2);
  seam_k<<<GRID, 256, 0, stream>>>(seam, out, cw1, cb1, cw2, cb2);
}

// Round 18
// 336.875 us; speedup vs baseline: 1.1152x; 1.1152x over previous
//
#include <hip/hip_runtime.h>

typedef unsigned short u16;
typedef unsigned char u8;
typedef __attribute__((ext_vector_type(8))) short short8;
typedef __attribute__((ext_vector_type(4))) float f32x4;

#define Bn 4096
#define Vn 20
#define Dn 768
#define Mn (Bn * Vn)   // 81920 rows
#define Nn (2 * Dn)    // 1536 packed m1/m2 columns

#define BM 256
#define BNt 256            // Wt rows per block tile (= 128 output e-columns)
#define NTILES (Nn / BNt)  // 6 N-tiles
#define GRID ((Mn / BM) * NTILES)   // 320 * 6 = 1920, %8 == 0
#define PANEL (256 * Dn)   // bytes per 256-row fp8 panel (196608)

#define SCL 32.0f          // fp8 pre-scale for X and W
#define ISCL2 (1.0f / 1024.0f)

typedef __attribute__((address_space(1))) void GV;
typedef __attribute__((address_space(3))) void LV;

__device__ __forceinline__ u16 f2bf(float f) {
  union { float f; unsigned u; } v; v.f = f;
  unsigned r = v.u + 0x7FFFu + ((v.u >> 16) & 1u);  // round-to-nearest-even
  return (u16)(r >> 16);
}
__device__ __forceinline__ float bf2f(u16 x) {
  union { unsigned u; float f; } v; v.u = ((unsigned)x) << 16; return v.f;
}

// Tiled fp8 layout (GLOBAL == LDS, linear copy): a 256-row x 32-byte K-slice
// (8192 B) is stored as [4 k-planes(8B)][128 row-pairs][2 rows][8 B]:
//   byte(q, kb) = (kb>>3)*2048 + (q>>1)*16 + (q&1)*8 + (kb&7)
// Fragment read (lane lo,hi: row q=R0+lo, k-bytes [hi*8,+8)):
//   addr = hi*2048 + (R0/2 + (lo>>1))*16 + (lo&1)*8
// -> each 16-lane b64 pass covers 128 CONTIGUOUS bytes = 32 banks, 0 conflicts.

// ---- kernel 1: softmax, 32 rows/block, LDS re-tile, all-coalesced I/O ------
// 512 thr = 32 rows x 16 lanes. Lane g, unit u owns elements e = g*4 + u*64
// (+c, c=0..3): global float4 reads are 256B-contiguous per 16-lane group.
// Element->tiled check: slice=(g>>3)+2u, plane=(g>>1)&3, byte=(g&1)*4+c ==
// byte(q,e) formula. 32-row LDS image: slice*1024 + plane*256 + (r>>1)*16 +
// (r&1)*8 (+byte); copy-out per (slice,plane) chunk is 256B contiguous at
// panel + slice*8192 + plane*2048 + (q0&255)*8.
__global__ __launch_bounds__(512) void softmax_k(const float* __restrict__ vf,
                                                 u8* __restrict__ X8) {
  __shared__ __align__(16) u8 lds[24576];
  const int t = threadIdx.x;
  const int r = t >> 4;                         // row-in-block 0..31
  const int g = t & 15;                         // lane-in-group
  const size_t q = (size_t)blockIdx.x * 32 + r;
  const float* src = vf + q * Dn + g * 4;
  float4 v[12];
  #pragma unroll
  for (int u = 0; u < 12; ++u) v[u] = *(const float4*)(src + u * 64);
  float mx = -1e30f;
  #pragma unroll
  for (int u = 0; u < 12; ++u)
    mx = fmaxf(mx, fmaxf(fmaxf(v[u].x, v[u].y), fmaxf(v[u].z, v[u].w)));
  #pragma unroll
  for (int off = 1; off < 16; off <<= 1) mx = fmaxf(mx, __shfl_xor(mx, off));
  float s = 0.f;
  #pragma unroll
  for (int u = 0; u < 12; ++u) {
    v[u].x = __expf(v[u].x - mx); v[u].y = __expf(v[u].y - mx);
    v[u].z = __expf(v[u].z - mx); v[u].w = __expf(v[u].w - mx);
    s += (v[u].x + v[u].y) + (v[u].z + v[u].w);
  }
  #pragma unroll
  for (int off = 1; off < 16; off <<= 1) s += __shfl_xor(s, off);
  const float inv = SCL / s;
  const int base = ((g >> 1) & 3) * 256 + (r >> 1) * 16 + (r & 1) * 8 + (g & 1) * 4;
  #pragma unroll
  for (int u = 0; u < 12; ++u) {
    unsigned pk = 0;
    pk = __builtin_amdgcn_cvt_pk_fp8_f32(v[u].x * inv, v[u].y * inv, pk, false);
    pk = __builtin_amdgcn_cvt_pk_fp8_f32(v[u].z * inv, v[u].w * inv, pk, true);
    *(unsigned*)(lds + ((g >> 3) + 2 * u) * 1024 + base) = pk;
  }
  __syncthreads();
  u8* dst = X8 + (size_t)(blockIdx.x >> 3) * PANEL + (blockIdx.x & 7) * 256;
  #pragma unroll
  for (int rd = 0; rd < 3; ++rd) {
    const int o = (rd * 512 + t) * 16;
    *(uint4*)(dst + (o >> 10) * 8192 + ((o >> 8) & 3) * 2048 + (o & 255)) =
        *(const uint4*)(lds + o);
  }
}

// ---- kernel 2: pack W1/W2 block-of-32 interleaved, fp8 x32, tiled ----------
__global__ __launch_bounds__(256) void build_wt_k(const float* __restrict__ W1,
                                                  const float* __restrict__ W2,
                                                  u8* __restrict__ Wt8) {
  int idx = blockIdx.x * 256 + threadIdx.x;        // over 768 * 192
  if (idx >= Dn * (Dn / 4)) return;
  int j = idx / (Dn / 4), d4 = (idx - j * (Dn / 4)) * 4;
  int b = j >> 5, c = j & 31;
  float4 a = *(const float4*)(W1 + (size_t)j * Dn + d4);
  float4 e = *(const float4*)(W2 + (size_t)j * Dn + d4);
  unsigned p1 = 0, p2 = 0;
  p1 = __builtin_amdgcn_cvt_pk_fp8_f32(a.x * SCL, a.y * SCL, p1, false);
  p1 = __builtin_amdgcn_cvt_pk_fp8_f32(a.z * SCL, a.w * SCL, p1, true);
  p2 = __builtin_amdgcn_cvt_pk_fp8_f32(e.x * SCL, e.y * SCL, p2, false);
  p2 = __builtin_amdgcn_cvt_pk_fp8_f32(e.z * SCL, e.w * SCL, p2, true);
  const int slice = d4 >> 5, plane = (d4 >> 3) & 3, bb = d4 & 7;
  const int j1 = b * 64 + c, j2 = b * 64 + 32 + c;
  const int q1 = j1 & 255, q2 = j2 & 255;
  *(unsigned*)(Wt8 + (size_t)(j1 >> 8) * PANEL + (size_t)slice * 8192
               + plane * 2048 + (q1 >> 1) * 16 + (q1 & 1) * 8 + bb) = p1;
  *(unsigned*)(Wt8 + (size_t)(j2 >> 8) * PANEL + (size_t)slice * 8192
               + plane * 2048 + (q2 >> 1) * 16 + (q2 & 1) * 8 + bb) = p2;
}

// -------- kernel 3: fp8 GEMM (8-phase, conflict-free tiled LDS) + conv ------
// Identical to the verified R17 kernel (gemm 240us, conflicts 9.8e5).
__global__ __launch_bounds__(512, 2) void gemm_fuse_k(
    const u8* __restrict__ X8, const u8* __restrict__ Wt8,
    const float* __restrict__ b1, const float* __restrict__ b2,
    const float* __restrict__ text, float* __restrict__ out,
    u16* __restrict__ seam,
    const float* __restrict__ cw1, const float* __restrict__ cb1,
    const float* __restrict__ cw2, const float* __restrict__ cb2) {
  __shared__ __align__(16) u16 smem[65536];   // 128 KiB (K-loop uses 64 KiB)
  u8* smem8 = (u8*)smem;

  const int h = blockIdx.x;                      // GRID = 1920 blocks, %8==0
  const int lin = (h & 7) * (GRID / 8) + (h >> 3);
  const int by = lin / NTILES, bx = lin - by * NTILES;
  const int brow = by * BM;

  const int t = threadIdx.x, w = t >> 6, l = t & 63;
  const int lo = l & 15, hi = l >> 4;
  const int wrr = w >> 2, wcc = w & 3;

  int offA[8], offB[4];
  #pragma unroll
  for (int m = 0; m < 8; ++m)
    offA[m] = hi * 2048 + (wrr * 64 + m * 8 + (lo >> 1)) * 16 + (lo & 1) * 8;
  #pragma unroll
  for (int n = 0; n < 4; ++n)
    offB[n] = hi * 2048 + (wcc * 32 + n * 8 + (lo >> 1)) * 16 + (lo & 1) * 8;

  // staging: tiled global slice is byte-identical to the LDS region
  const u8* gAp = X8 + (size_t)by * PANEL + t * 16;
  const u8* gBp = Wt8 + (size_t)bx * PANEL + t * 16;

#define STG_A(DST, SL) __builtin_amdgcn_global_load_lds( \
    (GV*)(gAp + (size_t)(SL) * 8192), (LV*)(smem8 + (DST) + w * 1024), 16, 0, 0)
#define STG_B(DST, SL) __builtin_amdgcn_global_load_lds( \
    (GV*)(gBp + (size_t)(SL) * 8192), (LV*)(smem8 + (DST) + w * 1024), 16, 0, 0)

  // prologue: T0Kh0, T1Kh0, T0Kh1, T1Kh1 (8 loads)
  STG_A(0, 0);              STG_B(16384, 0);          // T0 Kh0 -> slot0
  STG_A(32768, 2);          STG_B(49152, 2);          // T1 Kh0 -> slot1
  STG_A(8192, 1);           STG_B(24576, 1);          // T0 Kh1
  STG_A(40960, 3);          STG_B(57344, 3);          // T1 Kh1
  asm volatile("s_waitcnt vmcnt(6)" ::: "memory");    // T0-Kh0 resident
  __builtin_amdgcn_s_barrier();

  f32x4 acc[8][4] = {};
  long af[8], bb0, bb1;

#define PH(SB, KH, NH, NEWA, STG, VM) do {                                     \
    if (NEWA) { _Pragma("unroll") for (int m = 0; m < 8; ++m)                  \
      af[m] = *(const long*)(smem8 + (SB) + (KH) * 8192 + offA[m]); }          \
    bb0 = *(const long*)(smem8 + (SB) + 16384 + (KH) * 8192 + offB[(NH)*2]);   \
    bb1 = *(const long*)(smem8 + (SB) + 16384 + (KH) * 8192 + offB[(NH)*2+1]); \
    STG;                                                                       \
    __builtin_amdgcn_s_barrier();                                              \
    asm volatile("s_waitcnt lgkmcnt(0)" ::: "memory");                         \
    __builtin_amdgcn_sched_barrier(0);                                         \
    __builtin_amdgcn_s_setprio(1);                                             \
    _Pragma("unroll") for (int m = 0; m < 8; ++m) {                            \
      acc[m][(NH)*2]   = __builtin_amdgcn_mfma_f32_16x16x32_fp8_fp8(af[m], bb0, acc[m][(NH)*2],   0, 0, 0); \
      acc[m][(NH)*2+1] = __builtin_amdgcn_mfma_f32_16x16x32_fp8_fp8(af[m], bb1, acc[m][(NH)*2+1], 0, 0, 0); \
    }                                                                          \
    __builtin_amdgcn_s_setprio(0);                                             \
    VM;                                                                        \
    __builtin_amdgcn_s_barrier();                                              \
  } while (0)

#define VM2 asm volatile("s_waitcnt vmcnt(2)" ::: "memory")
#define VM0 asm volatile("s_waitcnt vmcnt(0)" ::: "memory")

  #pragma unroll
  for (int i = 0; i < 6; ++i) {
    const int sa = 2 * (2 * i + 1);    // slices of tile staged into slot1
    const int sb = 2 * (2 * i + 2);    // slices of tile staged into slot0
    PH(0, 0, 0, true,  if (i >= 1) STG_A(32768, sa),     ;  );
    PH(0, 0, 1, false, if (i >= 1) STG_B(49152, sa),     VM2);
    PH(0, 1, 0, true,  if (i >= 1) STG_A(40960, sa + 1), ;  );
    PH(0, 1, 1, false, if (i >= 1) STG_B(57344, sa + 1), VM2);
    PH(32768, 0, 0, true,  if (i <= 4) STG_A(0, sb),         ;  );
    PH(32768, 0, 1, false, if (i <= 4) STG_B(16384, sb),     if (i == 5) { VM0; } else { VM2; });
    PH(32768, 1, 0, true,  if (i <= 4) STG_A(8192, sb + 1),  ;  );
    PH(32768, 1, 1, false, if (i <= 4) STG_B(24576, sb + 1), if (i <= 4) { VM2; });
  }
#undef PH
#undef VM2
#undef VM0
#undef STG_A
#undef STG_B

  // ======================= fused-conv epilogue ==============================
  // vmcnt==0 here (i=5 P6 drained; P7/P8 stage nothing) -> smem reusable.
  const float w10 = cw1[0], w11 = cw1[1], w12 = cw1[2], c1b = cb1[0];
  const float w20 = cw2[0], w21 = cw2[1], w22 = cw2[2], c2b = cb2[0];

  u16* fsm = smem;           // fused [c][r]: idx = c*256 + (r ^ ((c&31)<<3))
  u16* tsm = smem + 32768;   // tmp, same layout

  // ---- E1: fused -> LDS bf16 (+ seam store for cols 0-3,124-127) ----
  #pragma unroll
  for (int n = 0; n < 2; ++n) {
    const int cl = wcc * 32 + n * 16 + lo;       // local col 0..127
    const int e  = bx * 128 + cl;
    const float B1 = b1[e], B2 = b2[e];
    #pragma unroll
    for (int m = 0; m < 8; ++m) {
      const int rl = wrr * 128 + m * 16 + hi * 4;
      uint2 pk;
      u16* pku = (u16*)&pk;
      #pragma unroll
      for (int r = 0; r < 4; ++r) {
        const int gr = brow + rl + r;
        const float v1 = acc[m][n][r] * ISCL2 + B1;
        const float v2 = acc[m][n + 2][r] * ISCL2 + B2;
        const float tf = text[(size_t)(gr / Vn) * Dn + e];
        pku[r] = f2bf(fmaxf(tf * v1 + v2, 0.0f));
      }
      *(uint2*)(fsm + cl * 256 + (rl ^ ((cl & 31) << 3))) = pk;
      const int sidx = (cl < 4) ? cl : ((cl >= 124) ? cl - 120 : -1);
      if (sidx >= 0)
        *(uint2*)(seam + ((size_t)(by * 6 + bx) * 8 + sidx) * 256 + rl) = pk;
    }
  }
  __syncthreads();

  // ---- E2: tmp = relu(conv1(fused)), per-thread col; own col kept in regs --
  const int cl = t & 127, rb = t >> 7;
  const int cL = cl ? cl - 1 : 0, cR = (cl < 127) ? cl + 1 : 127;
  short8 tC[8];
  #pragma unroll
  for (int j = 0; j < 8; ++j) {
    const int R = rb * 64 + j * 8;
    short8 sL = *(const short8*)(fsm + cL * 256 + (R ^ ((cL & 31) << 3)));
    short8 sC = *(const short8*)(fsm + cl * 256 + (R ^ ((cl & 31) << 3)));
    short8 sR = *(const short8*)(fsm + cR * 256 + (R ^ ((cR & 31) << 3)));
    short8 o;
    #pragma unroll
    for (int k = 0; k < 8; ++k) {
      float a = bf2f((u16)sL[k]), b = bf2f((u16)sC[k]), c = bf2f((u16)sR[k]);
      float v = fmaxf(fmaf(w10, a, fmaf(w11, b, fmaf(w12, c, c1b))), 0.0f);
      o[k] = (short)f2bf(v);
    }
    *(short8*)(tsm + cl * 256 + (R ^ ((cl & 31) << 3))) = o;
    tC[j] = o;
  }
  __syncthreads();

  // ---- E3: out = conv2(tmp), store interior cols 2..125 ----
  const bool wr_ok = (cl >= 2 && cl <= 125);
  #pragma unroll
  for (int j = 0; j < 8; ++j) {
    const int R = rb * 64 + j * 8;
    short8 tL = *(const short8*)(tsm + cL * 256 + (R ^ ((cL & 31) << 3)));
    short8 tR = *(const short8*)(tsm + cR * 256 + (R ^ ((cR & 31) << 3)));
    #pragma unroll
    for (int k = 0; k < 8; ++k) {
      float v = fmaf(w20, bf2f((u16)tL[k]),
                fmaf(w21, bf2f((u16)tC[j][k]),
                fmaf(w22, bf2f((u16)tR[k]), c2b)));
      if (wr_ok)
        out[(size_t)(brow + R + k) * Dn + bx * 128 + cl] = v;
    }
  }
}

// ------- kernel 4: seam cleanup — out cols {E0,E0+1,E0+126,E0+127} ---------
// Zero-pad semantics: conv2's pad gives tmp(-1)=tmp(768)=0 (NOT conv1 of
// zeros); conv1's pad gives fused(-1)=fused(768)=0 inside tmp(0)/tmp(767).
__global__ __launch_bounds__(256) void seam_k(const u16* __restrict__ seam,
                                              float* __restrict__ out,
                                              const float* __restrict__ cw1,
                                              const float* __restrict__ cb1,
                                              const float* __restrict__ cw2,
                                              const float* __restrict__ cb2) {
  const int bid = blockIdx.x;          // by*6+bx
  const int by = bid / 6, bx = bid - by * 6;
  const int r = threadIdx.x;
  const float w10 = cw1[0], w11 = cw1[1], w12 = cw1[2], c1b = cb1[0];
  const float w20 = cw2[0], w21 = cw2[1], w22 = cw2[2], c2b = cb2[0];
  #define SM(B, I) bf2f(seam[((size_t)(B) * 8 + (I)) * 256 + r])
  float fm2 = 0.f, fm1 = 0.f, fR0 = 0.f, fR1 = 0.f;
  if (bx > 0) { fm2 = SM(bid - 1, 6); fm1 = SM(bid - 1, 7); }
  if (bx < 5) { fR0 = SM(bid + 1, 0); fR1 = SM(bid + 1, 1); }
  const float f0 = SM(bid, 0), f1 = SM(bid, 1), f2 = SM(bid, 2), f3 = SM(bid, 3);
  const float f124 = SM(bid, 4), f125 = SM(bid, 5), f126 = SM(bid, 6), f127 = SM(bid, 7);
  #undef SM
  #define C1(a, b, c) fmaxf(fmaf(w10, (a), fmaf(w11, (b), fmaf(w12, (c), c1b))), 0.0f)
  const float tm1  = (bx > 0) ? C1(fm2, fm1, f0) : 0.0f;   // tmp(-1)=0 at edge
  const float t0   = C1(fm1, f0, f1);
  const float t1   = C1(f0, f1, f2);
  const float t2   = C1(f1, f2, f3);
  const float t125 = C1(f124, f125, f126);
  const float t126 = C1(f125, f126, f127);
  const float t127 = C1(f126, f127, fR0);
  const float t128 = (bx < 5) ? C1(f127, fR0, fR1) : 0.0f;  // tmp(768)=0 at edge
  #undef C1
  const size_t go = (size_t)(by * 256 + r) * Dn + bx * 128;
  out[go + 0]   = fmaf(w20, tm1,  fmaf(w21, t0,   fmaf(w22, t1,   c2b)));
  out[go + 1]   = fmaf(w20, t0,   fmaf(w21, t1,   fmaf(w22, t2,   c2b)));
  out[go + 126] = fmaf(w20, t125, fmaf(w21, t126, fmaf(w22, t127, c2b)));
  out[go + 127] = fmaf(w20, t126, fmaf(w21, t127, fmaf(w22, t128, c2b)));
}

extern "C" void kernel_launch(void* const* d_in, const int* in_sizes, int n_in,
                              void* d_out, int out_size, void* d_ws, size_t ws_size,
                              hipStream_t stream) {
  const float* text = (const float*)d_in[0];
  const float* vf   = (const float*)d_in[1];
  const float* W1   = (const float*)d_in[2];
  const float* b1   = (const float*)d_in[3];
  const float* W2   = (const float*)d_in[4];
  const float* b2   = (const float*)d_in[5];
  const float* cw1  = (const float*)d_in[6];
  const float* cb1  = (const float*)d_in[7];
  const float* cw2  = (const float*)d_in[8];
  const float* cb2  = (const float*)d_in[9];
  float* out = (float*)d_out;

  u8*  X8   = (u8*)d_ws;                                   // [320 panels] tiled fp8
  u8*  Wt8  = X8 + (size_t)Mn * Dn;                        // [6 panels] tiled fp8
  u16* seam = (u16*)(Wt8 + (size_t)Nn * Dn);               // [1920][8][256] bf16

  softmax_k<<<Mn / 32, 512, 0, stream>>>(vf, X8);
  build_wt_k<<<(Dn * (Dn / 4) + 255) / 256, 256, 0, stream>>>(W1, W2, Wt8);
  gemm_fuse_k<<<GRID, 512, 0, stream>>>(X8, Wt8, b1, b2, text, out, seam,
                                        cw1, cb1, cw2, cb2);
  seam_k<<<GRID, 256, 0, stream>>>(seam, out, cw1, cb1, cw2, cb2);
}

// Round 19
// 326.139 us; speedup vs baseline: 1.1519x; 1.0329x over previous
//
#include <hip/hip_runtime.h>

typedef unsigned short u16;
typedef unsigned char u8;
typedef __attribute__((ext_vector_type(8))) short short8;
typedef __attribute__((ext_vector_type(4))) float f32x4;
typedef __attribute__((ext_vector_type(2))) long long2v;

#define Bn 4096
#define Vn 20
#define Dn 768
#define Mn (Bn * Vn)   // 81920 rows
#define Nn (2 * Dn)    // 1536 packed m1/m2 columns

#define BM 256
#define BNt 256            // Wt rows per block tile (= 128 output e-columns)
#define NTILES (Nn / BNt)  // 6 N-tiles
#define GRID ((Mn / BM) * NTILES)   // 320 * 6 = 1920, %8 == 0
#define PANEL (256 * Dn)   // bytes per 256-row fp8 panel (196608)

#define SCL 32.0f          // fp8 pre-scale for X and W
#define ISCL2 (1.0f / 1024.0f)

typedef __attribute__((address_space(1))) void GV;
typedef __attribute__((address_space(3))) void LV;

__device__ __forceinline__ u16 f2bf(float f) {
  union { float f; unsigned u; } v; v.f = f;
  unsigned r = v.u + 0x7FFFu + ((v.u >> 16) & 1u);  // round-to-nearest-even
  return (u16)(r >> 16);
}
__device__ __forceinline__ float bf2f(u16 x) {
  union { unsigned u; float f; } v; v.u = ((unsigned)x) << 16; return v.f;
}

// Tiled fp8 layout v2 (GLOBAL == LDS, identity copy): a 256-row x 64-byte
// K-tile (16384 B region) is stored as [4 hi-planes(4096B)][256 rows][16B]:
//   byte(q, kb) = hi*4096 + q*16 + half*8 + b,
//   half = kb>>5, hi = (kb>>3)&3, b = kb&7   (kb = k-byte 0..63 in tile)
// Fragment read (lane lo,hi; row q=R0+lo): ONE ds_read_b128 at
//   hi*4096 + q*16 delivers both K-halves ({bytes0-7}=kk0, {8-15}=kk1).
// 16-lane pass = 256 contiguous bytes -> conflict-free.

// ---- kernel 1: softmax, 32 rows/block, LDS re-tile (layout v2) -------------
// 512 thr = 32 rows x 16 lanes. Lane g, unit u owns e = g*4 + u*64 (+c):
// global float4 reads 256B-contiguous per 16-lane group. For element e:
// K-tile u, kb=g*4+c -> half=g>>3, hi=(g>>1)&3, b=(g&1)*4+c.
// 32-row LDS image: u*2048 + hi*512 + r*16 + half*8 + (g&1)*4 (+c).
// Copy-out chunk (u,hi): LDS u*2048+hi*512 (512B) -> global u*16384+hi*4096
// + q0*16 (512B contiguous), q0 = (blockIdx&7)*32.
__global__ __launch_bounds__(512) void softmax_k(const float* __restrict__ vf,
                                                 u8* __restrict__ X8) {
  __shared__ __align__(16) u8 lds[24576];
  const int t = threadIdx.x;
  const int r = t >> 4;                         // row-in-block 0..31
  const int g = t & 15;                         // lane-in-group
  const size_t q = (size_t)blockIdx.x * 32 + r;
  const float* src = vf + q * Dn + g * 4;
  float4 v[12];
  #pragma unroll
  for (int u = 0; u < 12; ++u) v[u] = *(const float4*)(src + u * 64);
  float mx = -1e30f;
  #pragma unroll
  for (int u = 0; u < 12; ++u)
    mx = fmaxf(mx, fmaxf(fmaxf(v[u].x, v[u].y), fmaxf(v[u].z, v[u].w)));
  #pragma unroll
  for (int off = 1; off < 16; off <<= 1) mx = fmaxf(mx, __shfl_xor(mx, off));
  float s = 0.f;
  #pragma unroll
  for (int u = 0; u < 12; ++u) {
    v[u].x = __expf(v[u].x - mx); v[u].y = __expf(v[u].y - mx);
    v[u].z = __expf(v[u].z - mx); v[u].w = __expf(v[u].w - mx);
    s += (v[u].x + v[u].y) + (v[u].z + v[u].w);
  }
  #pragma unroll
  for (int off = 1; off < 16; off <<= 1) s += __shfl_xor(s, off);
  const float inv = SCL / s;
  const int base = ((g >> 1) & 3) * 512 + r * 16 + (g >> 3) * 8 + (g & 1) * 4;
  #pragma unroll
  for (int u = 0; u < 12; ++u) {
    unsigned pk = 0;
    pk = __builtin_amdgcn_cvt_pk_fp8_f32(v[u].x * inv, v[u].y * inv, pk, false);
    pk = __builtin_amdgcn_cvt_pk_fp8_f32(v[u].z * inv, v[u].w * inv, pk, true);
    *(unsigned*)(lds + u * 2048 + base) = pk;
  }
  __syncthreads();
  u8* dst = X8 + (size_t)(blockIdx.x >> 3) * PANEL + (blockIdx.x & 7) * 512;
  #pragma unroll
  for (int rd = 0; rd < 3; ++rd) {
    const int o = (rd * 512 + t) * 16;
    const int chunk = o >> 9;
    *(uint4*)(dst + (chunk >> 2) * 16384 + (chunk & 3) * 4096 + (o & 511)) =
        *(const uint4*)(lds + o);
  }
}

// ---- kernel 2: pack W1/W2 block-of-32 interleaved, fp8 x32, layout v2 ------
__global__ __launch_bounds__(256) void build_wt_k(const float* __restrict__ W1,
                                                  const float* __restrict__ W2,
                                                  u8* __restrict__ Wt8) {
  int idx = blockIdx.x * 256 + threadIdx.x;        // over 768 * 192
  if (idx >= Dn * (Dn / 4)) return;
  int j = idx / (Dn / 4), d4 = (idx - j * (Dn / 4)) * 4;
  int b = j >> 5, c = j & 31;
  float4 a = *(const float4*)(W1 + (size_t)j * Dn + d4);
  float4 e = *(const float4*)(W2 + (size_t)j * Dn + d4);
  unsigned p1 = 0, p2 = 0;
  p1 = __builtin_amdgcn_cvt_pk_fp8_f32(a.x * SCL, a.y * SCL, p1, false);
  p1 = __builtin_amdgcn_cvt_pk_fp8_f32(a.z * SCL, a.w * SCL, p1, true);
  p2 = __builtin_amdgcn_cvt_pk_fp8_f32(e.x * SCL, e.y * SCL, p2, false);
  p2 = __builtin_amdgcn_cvt_pk_fp8_f32(e.z * SCL, e.w * SCL, p2, true);
  const size_t off = (size_t)(d4 >> 6) * 16384 + ((d4 >> 3) & 3) * 4096
                   + ((d4 >> 5) & 1) * 8 + (d4 & 7);
  const int j1 = b * 64 + c, j2 = b * 64 + 32 + c;
  *(unsigned*)(Wt8 + (size_t)(j1 >> 8) * PANEL + off + (j1 & 255) * 16) = p1;
  *(unsigned*)(Wt8 + (size_t)(j2 >> 8) * PANEL + off + (j2 & 255) * 16) = p2;
}

// -------- kernel 3: fp8 GEMM, 2-phase/K-tile 3-slot ring + fused conv -------
// 24 phases (vs 48): per K-tile T {PH1: af[8]+b0,b1 b128 reads, stage A(T+2);
// barrier; lgkm0; 32 MFMA | PH2: b2,b3 reads, stage B(T+2); barrier; lgkm0;
// 32 MFMA; vmcnt(4)}. Ledger: tile T's 4 loads issue during T-2; at T-1.PH2
// end vmcnt(4) leaves only T+1's 4 outstanding => T resident. WAR: stage into
// slot (T+2)%3 overwrites tile T-1's slot, last read (lgkm-complete) before
// T-1.PH2's trailing barrier. Tail: VM0 at T=10 (T11 resident + epilogue
// drain); T=11 stages nothing.
__global__ __launch_bounds__(512, 2) void gemm_fuse_k(
    const u8* __restrict__ X8, const u8* __restrict__ Wt8,
    const float* __restrict__ b1, const float* __restrict__ b2,
    const float* __restrict__ text, float* __restrict__ out,
    u16* __restrict__ seam,
    const float* __restrict__ cw1, const float* __restrict__ cb1,
    const float* __restrict__ cw2, const float* __restrict__ cb2) {
  __shared__ __align__(16) u16 smem[65536];   // 128 KiB (K-loop uses 96 KiB)
  u8* smem8 = (u8*)smem;

  const int h = blockIdx.x;                      // GRID = 1920 blocks, %8==0
  const int lin = (h & 7) * (GRID / 8) + (h >> 3);
  const int by = lin / NTILES, bx = lin - by * NTILES;
  const int brow = by * BM;

  const int t = threadIdx.x, w = t >> 6, l = t & 63;
  const int lo = l & 15, hi = l >> 4;
  const int wrr = w >> 2, wcc = w & 3;

  int offA[8], offB[4];
  #pragma unroll
  for (int m = 0; m < 8; ++m)
    offA[m] = hi * 4096 + (wrr * 128 + m * 16 + lo) * 16;
  #pragma unroll
  for (int n = 0; n < 4; ++n)
    offB[n] = 16384 + hi * 4096 + (wcc * 64 + n * 16 + lo) * 16;

  // staging: tiled global region is byte-identical to the LDS region
  const u8* gAp = X8 + (size_t)by * PANEL + t * 16;
  const u8* gBp = Wt8 + (size_t)bx * PANEL + t * 16;

#define STG_A(SB, T) do {                                                      \
    __builtin_amdgcn_global_load_lds((GV*)(gAp + (size_t)(T) * 16384),         \
        (LV*)(smem8 + (SB) + w * 1024), 16, 0, 0);                             \
    __builtin_amdgcn_global_load_lds((GV*)(gAp + (size_t)(T) * 16384 + 8192),  \
        (LV*)(smem8 + (SB) + 8192 + w * 1024), 16, 0, 0); } while (0)
#define STG_B(SB, T) do {                                                      \
    __builtin_amdgcn_global_load_lds((GV*)(gBp + (size_t)(T) * 16384),         \
        (LV*)(smem8 + (SB) + 16384 + w * 1024), 16, 0, 0);                     \
    __builtin_amdgcn_global_load_lds((GV*)(gBp + (size_t)(T) * 16384 + 8192),  \
        (LV*)(smem8 + (SB) + 24576 + w * 1024), 16, 0, 0); } while (0)

  // prologue: tiles 0,1 (8 loads); vmcnt(4) -> T0 resident
  STG_A(0, 0);     STG_B(0, 0);
  STG_A(32768, 1); STG_B(32768, 1);
  asm volatile("s_waitcnt vmcnt(4)" ::: "memory");
  __builtin_amdgcn_s_barrier();

  f32x4 acc[8][4] = {};
  long2v af[8], bb0, bb1;

  #pragma unroll
  for (int T = 0; T < 12; ++T) {
    const int cs = (T % 3) * 32768;          // compute slot base
    const int ss = ((T + 2) % 3) * 32768;    // stage slot base
    const bool st = (T <= 9);

    // ---- PH1: n = 0,1 ----
    #pragma unroll
    for (int m = 0; m < 8; ++m)
      af[m] = *(const long2v*)(smem8 + cs + offA[m]);
    bb0 = *(const long2v*)(smem8 + cs + offB[0]);
    bb1 = *(const long2v*)(smem8 + cs + offB[1]);
    if (st) STG_A(ss, T + 2);
    __builtin_amdgcn_s_barrier();
    asm volatile("s_waitcnt lgkmcnt(0)" ::: "memory");
    __builtin_amdgcn_sched_barrier(0);
    __builtin_amdgcn_s_setprio(1);
    #pragma unroll
    for (int m = 0; m < 8; ++m) {
      acc[m][0] = __builtin_amdgcn_mfma_f32_16x16x32_fp8_fp8(af[m][0], bb0[0], acc[m][0], 0, 0, 0);
      acc[m][0] = __builtin_amdgcn_mfma_f32_16x16x32_fp8_fp8(af[m][1], bb0[1], acc[m][0], 0, 0, 0);
      acc[m][1] = __builtin_amdgcn_mfma_f32_16x16x32_fp8_fp8(af[m][0], bb1[0], acc[m][1], 0, 0, 0);
      acc[m][1] = __builtin_amdgcn_mfma_f32_16x16x32_fp8_fp8(af[m][1], bb1[1], acc[m][1], 0, 0, 0);
    }
    __builtin_amdgcn_s_setprio(0);
    __builtin_amdgcn_s_barrier();

    // ---- PH2: n = 2,3 ----
    bb0 = *(const long2v*)(smem8 + cs + offB[2]);
    bb1 = *(const long2v*)(smem8 + cs + offB[3]);
    if (st) STG_B(ss, T + 2);
    __builtin_amdgcn_s_barrier();
    asm volatile("s_waitcnt lgkmcnt(0)" ::: "memory");
    __builtin_amdgcn_sched_barrier(0);
    __builtin_amdgcn_s_setprio(1);
    #pragma unroll
    for (int m = 0; m < 8; ++m) {
      acc[m][2] = __builtin_amdgcn_mfma_f32_16x16x32_fp8_fp8(af[m][0], bb0[0], acc[m][2], 0, 0, 0);
      acc[m][2] = __builtin_amdgcn_mfma_f32_16x16x32_fp8_fp8(af[m][1], bb0[1], acc[m][2], 0, 0, 0);
      acc[m][3] = __builtin_amdgcn_mfma_f32_16x16x32_fp8_fp8(af[m][0], bb1[0], acc[m][3], 0, 0, 0);
      acc[m][3] = __builtin_amdgcn_mfma_f32_16x16x32_fp8_fp8(af[m][1], bb1[1], acc[m][3], 0, 0, 0);
    }
    __builtin_amdgcn_s_setprio(0);
    if (T <= 9)       asm volatile("s_waitcnt vmcnt(4)" ::: "memory");
    else if (T == 10) asm volatile("s_waitcnt vmcnt(0)" ::: "memory");
    __builtin_amdgcn_s_barrier();
  }
#undef STG_A
#undef STG_B

  // ======================= fused-conv epilogue ==============================
  // vmcnt==0 (drained at T=10; T=11 stages nothing) -> smem reusable.
  const float w10 = cw1[0], w11 = cw1[1], w12 = cw1[2], c1b = cb1[0];
  const float w20 = cw2[0], w21 = cw2[1], w22 = cw2[2], c2b = cb2[0];

  u16* fsm = smem;           // fused [c][r]: idx = c*256 + (r ^ ((c&31)<<3))
  u16* tsm = smem + 32768;   // tmp, same layout

  // ---- E1: fused -> LDS bf16 (+ seam store for cols 0-3,124-127) ----
  #pragma unroll
  for (int n = 0; n < 2; ++n) {
    const int cl = wcc * 32 + n * 16 + lo;       // local col 0..127
    const int e  = bx * 128 + cl;
    const float B1 = b1[e], B2 = b2[e];
    #pragma unroll
    for (int m = 0; m < 8; ++m) {
      const int rl = wrr * 128 + m * 16 + hi * 4;
      uint2 pk;
      u16* pku = (u16*)&pk;
      #pragma unroll
      for (int r = 0; r < 4; ++r) {
        const int gr = brow + rl + r;
        const float v1 = acc[m][n][r] * ISCL2 + B1;
        const float v2 = acc[m][n + 2][r] * ISCL2 + B2;
        const float tf = text[(size_t)(gr / Vn) * Dn + e];
        pku[r] = f2bf(fmaxf(tf * v1 + v2, 0.0f));
      }
      *(uint2*)(fsm + cl * 256 + (rl ^ ((cl & 31) << 3))) = pk;
      const int sidx = (cl < 4) ? cl : ((cl >= 124) ? cl - 120 : -1);
      if (sidx >= 0)
        *(uint2*)(seam + ((size_t)(by * 6 + bx) * 8 + sidx) * 256 + rl) = pk;
    }
  }
  __syncthreads();

  // ---- E2: tmp = relu(conv1(fused)), per-thread col; own col kept in regs --
  const int cl = t & 127, rb = t >> 7;
  const int cL = cl ? cl - 1 : 0, cR = (cl < 127) ? cl + 1 : 127;
  short8 tC[8];
  #pragma unroll
  for (int j = 0; j < 8; ++j) {
    const int R = rb * 64 + j * 8;
    short8 sL = *(const short8*)(fsm + cL * 256 + (R ^ ((cL & 31) << 3)));
    short8 sC = *(const short8*)(fsm + cl * 256 + (R ^ ((cl & 31) << 3)));
    short8 sR = *(const short8*)(fsm + cR * 256 + (R ^ ((cR & 31) << 3)));
    short8 o;
    #pragma unroll
    for (int k = 0; k < 8; ++k) {
      float a = bf2f((u16)sL[k]), b = bf2f((u16)sC[k]), c = bf2f((u16)sR[k]);
      float v = fmaxf(fmaf(w10, a, fmaf(w11, b, fmaf(w12, c, c1b))), 0.0f);
      o[k] = (short)f2bf(v);
    }
    *(short8*)(tsm + cl * 256 + (R ^ ((cl & 31) << 3))) = o;
    tC[j] = o;
  }
  __syncthreads();

  // ---- E3: out = conv2(tmp), store interior cols 2..125 ----
  const bool wr_ok = (cl >= 2 && cl <= 125);
  #pragma unroll
  for (int j = 0; j < 8; ++j) {
    const int R = rb * 64 + j * 8;
    short8 tL = *(const short8*)(tsm + cL * 256 + (R ^ ((cL & 31) << 3)));
    short8 tR = *(const short8*)(tsm + cR * 256 + (R ^ ((cR & 31) << 3)));
    #pragma unroll
    for (int k = 0; k < 8; ++k) {
      float v = fmaf(w20, bf2f((u16)tL[k]),
                fmaf(w21, bf2f((u16)tC[j][k]),
                fmaf(w22, bf2f((u16)tR[k]), c2b)));
      if (wr_ok)
        out[(size_t)(brow + R + k) * Dn + bx * 128 + cl] = v;
    }
  }
}

// ------- kernel 4: seam cleanup — out cols {E0,E0+1,E0+126,E0+127} ---------
// Zero-pad semantics: conv2's pad gives tmp(-1)=tmp(768)=0 (NOT conv1 of
// zeros); conv1's pad gives fused(-1)=fused(768)=0 inside tmp(0)/tmp(767).
__global__ __launch_bounds__(256) void seam_k(const u16* __restrict__ seam,
                                              float* __restrict__ out,
                                              const float* __restrict__ cw1,
                                              const float* __restrict__ cb1,
                                              const float* __restrict__ cw2,
                                              const float* __restrict__ cb2) {
  const int bid = blockIdx.x;          // by*6+bx
  const int by = bid / 6, bx = bid - by * 6;
  const int r = threadIdx.x;
  const float w10 = cw1[0], w11 = cw1[1], w12 = cw1[2], c1b = cb1[0];
  const float w20 = cw2[0], w21 = cw2[1], w22 = cw2[2], c2b = cb2[0];
  #define SM(B, I) bf2f(seam[((size_t)(B) * 8 + (I)) * 256 + r])
  float fm2 = 0.f, fm1 = 0.f, fR0 = 0.f, fR1 = 0.f;
  if (bx > 0) { fm2 = SM(bid - 1, 6); fm1 = SM(bid - 1, 7); }
  if (bx < 5) { fR0 = SM(bid + 1, 0); fR1 = SM(bid + 1, 1); }
  const float f0 = SM(bid, 0), f1 = SM(bid, 1), f2 = SM(bid, 2), f3 = SM(bid, 3);
  const float f124 = SM(bid, 4), f125 = SM(bid, 5), f126 = SM(bid, 6), f127 = SM(bid, 7);
  #undef SM
  #define C1(a, b, c) fmaxf(fmaf(w10, (a), fmaf(w11, (b), fmaf(w12, (c), c1b))), 0.0f)
  const float tm1  = (bx > 0) ? C1(fm2, fm1, f0) : 0.0f;   // tmp(-1)=0 at edge
  const float t0   = C1(fm1, f0, f1);
  const float t1   = C1(f0, f1, f2);
  const float t2   = C1(f1, f2, f3);
  const float t125 = C1(f124, f125, f126);
  const float t126 = C1(f125, f126, f127);
  const float t127 = C1(f126, f127, fR0);
  const float t128 = (bx < 5) ? C1(f127, fR0, fR1) : 0.0f;  // tmp(768)=0 at edge
  #undef C1
  const size_t go = (size_t)(by * 256 + r) * Dn + bx * 128;
  out[go + 0]   = fmaf(w20, tm1,  fmaf(w21, t0,   fmaf(w22, t1,   c2b)));
  out[go + 1]   = fmaf(w20, t0,   fmaf(w21, t1,   fmaf(w22, t2,   c2b)));
  out[go + 126] = fmaf(w20, t125, fmaf(w21, t126, fmaf(w22, t127, c2b)));
  out[go + 127] = fmaf(w20, t126, fmaf(w21, t127, fmaf(w22, t128, c2b)));
}

extern "C" void kernel_launch(void* const* d_in, const int* in_sizes, int n_in,
                              void* d_out, int out_size, void* d_ws, size_t ws_size,
                              hipStream_t stream) {
  const float* text = (const float*)d_in[0];
  const float* vf   = (const float*)d_in[1];
  const float* W1   = (const float*)d_in[2];
  const float* b1   = (const float*)d_in[3];
  const float* W2   = (const float*)d_in[4];
  const float* b2   = (const float*)d_in[5];
  const float* cw1  = (const float*)d_in[6];
  const float* cb1  = (const float*)d_in[7];
  const float* cw2  = (const float*)d_in[8];
  const float* cb2  = (const float*)d_in[9];
  float* out = (float*)d_out;

  u8*  X8   = (u8*)d_ws;                                   // [320 panels] tiled fp8 v2
  u8*  Wt8  = X8 + (size_t)Mn * Dn;                        // [6 panels] tiled fp8 v2
  u16* seam = (u16*)(Wt8 + (size_t)Nn * Dn);               // [1920][8][256] bf16

  softmax_k<<<Mn / 32, 512, 0, stream>>>(vf, X8);
  build_wt_k<<<(Dn * (Dn / 4) + 255) / 256, 256, 0, stream>>>(W1, W2, Wt8);
  gemm_fuse_k<<<GRID, 512, 0, stream>>>(X8, Wt8, b1, b2, text, out, seam,
                                        cw1, cb1, cw2, cb2);
  seam_k<<<GRID, 256, 0, stream>>>(seam, out, cw1, cb1, cw2, cb2);
}

// Round 20
// 324.616 us; speedup vs baseline: 1.1573x; 1.0047x over previous
//
#include <hip/hip_runtime.h>

typedef unsigned short u16;
typedef unsigned char u8;
typedef __attribute__((ext_vector_type(8))) short short8;
typedef __attribute__((ext_vector_type(4))) float f32x4;
typedef __attribute__((ext_vector_type(2))) long long2v;

#define Bn 4096
#define Vn 20
#define Dn 768
#define Mn (Bn * Vn)   // 81920 rows
#define Nn (2 * Dn)    // 1536 packed m1/m2 columns

#define BM 256
#define BNt 256            // Wt rows per block tile (= 128 output e-columns)
#define NTILES (Nn / BNt)  // 6 N-tiles
#define GRID ((Mn / BM) * NTILES)   // 320 * 6 = 1920, %8 == 0
#define PANEL (256 * Dn)   // bytes per 256-row fp8 panel (196608)

#define SCL 32.0f          // fp8 pre-scale for X and W
#define ISCL2 (1.0f / 1024.0f)

typedef __attribute__((address_space(1))) void GV;
typedef __attribute__((address_space(3))) void LV;

__device__ __forceinline__ u16 f2bf(float f) {
  union { float f; unsigned u; } v; v.f = f;
  unsigned r = v.u + 0x7FFFu + ((v.u >> 16) & 1u);  // round-to-nearest-even
  return (u16)(r >> 16);
}
__device__ __forceinline__ float bf2f(u16 x) {
  union { unsigned u; float f; } v; v.u = ((unsigned)x) << 16; return v.f;
}

// Tiled fp8 layout v2 (GLOBAL == LDS, identity copy): a 256-row x 64-byte
// K-tile (16384 B region) is stored as [4 hi-planes(4096B)][256 rows][16B]:
//   byte(q, kb) = hi*4096 + q*16 + half*8 + b,
//   half = kb>>5, hi = (kb>>3)&3, b = kb&7   (kb = k-byte 0..63 in tile)
// Fragment read (lane lo,hi; row q=R0+lo): ONE ds_read_b128 at
//   hi*4096 + q*16 delivers both K-halves ({bytes0-7}=kk0, {8-15}=kk1).
// 16-lane pass = 256 contiguous bytes -> conflict-free.

// ---- kernel 1: softmax, 32 rows/block, LDS re-tile (layout v2) -------------
__global__ __launch_bounds__(512) void softmax_k(const float* __restrict__ vf,
                                                 u8* __restrict__ X8) {
  __shared__ __align__(16) u8 lds[24576];
  const int t = threadIdx.x;
  const int r = t >> 4;                         // row-in-block 0..31
  const int g = t & 15;                         // lane-in-group
  const size_t q = (size_t)blockIdx.x * 32 + r;
  const float* src = vf + q * Dn + g * 4;
  float4 v[12];
  #pragma unroll
  for (int u = 0; u < 12; ++u) v[u] = *(const float4*)(src + u * 64);
  float mx = -1e30f;
  #pragma unroll
  for (int u = 0; u < 12; ++u)
    mx = fmaxf(mx, fmaxf(fmaxf(v[u].x, v[u].y), fmaxf(v[u].z, v[u].w)));
  #pragma unroll
  for (int off = 1; off < 16; off <<= 1) mx = fmaxf(mx, __shfl_xor(mx, off));
  float s = 0.f;
  #pragma unroll
  for (int u = 0; u < 12; ++u) {
    v[u].x = __expf(v[u].x - mx); v[u].y = __expf(v[u].y - mx);
    v[u].z = __expf(v[u].z - mx); v[u].w = __expf(v[u].w - mx);
    s += (v[u].x + v[u].y) + (v[u].z + v[u].w);
  }
  #pragma unroll
  for (int off = 1; off < 16; off <<= 1) s += __shfl_xor(s, off);
  const float inv = SCL / s;
  const int base = ((g >> 1) & 3) * 512 + r * 16 + (g >> 3) * 8 + (g & 1) * 4;
  #pragma unroll
  for (int u = 0; u < 12; ++u) {
    unsigned pk = 0;
    pk = __builtin_amdgcn_cvt_pk_fp8_f32(v[u].x * inv, v[u].y * inv, pk, false);
    pk = __builtin_amdgcn_cvt_pk_fp8_f32(v[u].z * inv, v[u].w * inv, pk, true);
    *(unsigned*)(lds + u * 2048 + base) = pk;
  }
  __syncthreads();
  u8* dst = X8 + (size_t)(blockIdx.x >> 3) * PANEL + (blockIdx.x & 7) * 512;
  #pragma unroll
  for (int rd = 0; rd < 3; ++rd) {
    const int o = (rd * 512 + t) * 16;
    const int chunk = o >> 9;
    *(uint4*)(dst + (chunk >> 2) * 16384 + (chunk & 3) * 4096 + (o & 511)) =
        *(const uint4*)(lds + o);
  }
}

// ---- kernel 2: pack W1/W2 block-of-32 interleaved, fp8 x32, layout v2 ------
__global__ __launch_bounds__(256) void build_wt_k(const float* __restrict__ W1,
                                                  const float* __restrict__ W2,
                                                  u8* __restrict__ Wt8) {
  int idx = blockIdx.x * 256 + threadIdx.x;        // over 768 * 192
  if (idx >= Dn * (Dn / 4)) return;
  int j = idx / (Dn / 4), d4 = (idx - j * (Dn / 4)) * 4;
  int b = j >> 5, c = j & 31;
  float4 a = *(const float4*)(W1 + (size_t)j * Dn + d4);
  float4 e = *(const float4*)(W2 + (size_t)j * Dn + d4);
  unsigned p1 = 0, p2 = 0;
  p1 = __builtin_amdgcn_cvt_pk_fp8_f32(a.x * SCL, a.y * SCL, p1, false);
  p1 = __builtin_amdgcn_cvt_pk_fp8_f32(a.z * SCL, a.w * SCL, p1, true);
  p2 = __builtin_amdgcn_cvt_pk_fp8_f32(e.x * SCL, e.y * SCL, p2, false);
  p2 = __builtin_amdgcn_cvt_pk_fp8_f32(e.z * SCL, e.w * SCL, p2, true);
  const size_t off = (size_t)(d4 >> 6) * 16384 + ((d4 >> 3) & 3) * 4096
                   + ((d4 >> 5) & 1) * 8 + (d4 & 7);
  const int j1 = b * 64 + c, j2 = b * 64 + 32 + c;
  *(unsigned*)(Wt8 + (size_t)(j1 >> 8) * PANEL + off + (j1 & 255) * 16) = p1;
  *(unsigned*)(Wt8 + (size_t)(j2 >> 8) * PANEL + off + (j2 & 255) * 16) = p2;
}

// -------- kernel 3: fp8 GEMM, 1-phase/K-tile 3-slot ring + fused conv -------
// 12 phases (vs 24): per K-tile T {read af[8]+bb[4] (12 b128); stage
// A(T+2)+B(T+2) (4 loads); barrier; lgkm0; prio1 64-MFMA cluster prio0;
// vmcnt; barrier}. Ledger: at end-of-T vmcnt(4) leaves only T+2's 4 loads
// outstanding => T+1 resident. WAR: stage into slot (T+2)%3 overwrites tile
// T-1's slot; its readers lgkm-drained before T-1's trailing barrier which
// precedes T's stage issue. Tail: VM0 at T=10; T=11 stages nothing ->
// epilogue LDS reuse safe after the loop's final barrier.
__global__ __launch_bounds__(512, 2) void gemm_fuse_k(
    const u8* __restrict__ X8, const u8* __restrict__ Wt8,
    const float* __restrict__ b1, const float* __restrict__ b2,
    const float* __restrict__ text, float* __restrict__ out,
    u16* __restrict__ seam,
    const float* __restrict__ cw1, const float* __restrict__ cb1,
    const float* __restrict__ cw2, const float* __restrict__ cb2) {
  __shared__ __align__(16) u16 smem[65536];   // 128 KiB (K-loop uses 96 KiB)
  u8* smem8 = (u8*)smem;

  const int h = blockIdx.x;                      // GRID = 1920 blocks, %8==0
  const int lin = (h & 7) * (GRID / 8) + (h >> 3);
  const int by = lin / NTILES, bx = lin - by * NTILES;
  const int brow = by * BM;

  const int t = threadIdx.x, w = t >> 6, l = t & 63;
  const int lo = l & 15, hi = l >> 4;
  const int wrr = w >> 2, wcc = w & 3;

  int offA[8], offB[4];
  #pragma unroll
  for (int m = 0; m < 8; ++m)
    offA[m] = hi * 4096 + (wrr * 128 + m * 16 + lo) * 16;
  #pragma unroll
  for (int n = 0; n < 4; ++n)
    offB[n] = 16384 + hi * 4096 + (wcc * 64 + n * 16 + lo) * 16;

  // staging: tiled global region is byte-identical to the LDS region
  const u8* gAp = X8 + (size_t)by * PANEL + t * 16;
  const u8* gBp = Wt8 + (size_t)bx * PANEL + t * 16;

#define STG_A(SB, T) do {                                                      \
    __builtin_amdgcn_global_load_lds((GV*)(gAp + (size_t)(T) * 16384),         \
        (LV*)(smem8 + (SB) + w * 1024), 16, 0, 0);                             \
    __builtin_amdgcn_global_load_lds((GV*)(gAp + (size_t)(T) * 16384 + 8192),  \
        (LV*)(smem8 + (SB) + 8192 + w * 1024), 16, 0, 0); } while (0)
#define STG_B(SB, T) do {                                                      \
    __builtin_amdgcn_global_load_lds((GV*)(gBp + (size_t)(T) * 16384),         \
        (LV*)(smem8 + (SB) + 16384 + w * 1024), 16, 0, 0);                     \
    __builtin_amdgcn_global_load_lds((GV*)(gBp + (size_t)(T) * 16384 + 8192),  \
        (LV*)(smem8 + (SB) + 24576 + w * 1024), 16, 0, 0); } while (0)

  // prologue: tiles 0,1 (8 loads); vmcnt(4) -> T0 resident
  STG_A(0, 0);     STG_B(0, 0);
  STG_A(32768, 1); STG_B(32768, 1);
  asm volatile("s_waitcnt vmcnt(4)" ::: "memory");
  __builtin_amdgcn_s_barrier();

  f32x4 acc[8][4] = {};
  long2v af[8], bb[4];

  #pragma unroll
  for (int T = 0; T < 12; ++T) {
    const int cs = (T % 3) * 32768;          // compute slot base
    const int ss = ((T + 2) % 3) * 32768;    // stage slot base

    // ---- single phase: full K-tile (12 b128 reads, 64 MFMA) ----
    #pragma unroll
    for (int m = 0; m < 8; ++m)
      af[m] = *(const long2v*)(smem8 + cs + offA[m]);
    #pragma unroll
    for (int n = 0; n < 4; ++n)
      bb[n] = *(const long2v*)(smem8 + cs + offB[n]);
    if (T <= 9) { STG_A(ss, T + 2); STG_B(ss, T + 2); }
    __builtin_amdgcn_s_barrier();
    asm volatile("s_waitcnt lgkmcnt(0)" ::: "memory");
    __builtin_amdgcn_sched_barrier(0);
    __builtin_amdgcn_s_setprio(1);
    #pragma unroll
    for (int m = 0; m < 8; ++m) {
      #pragma unroll
      for (int n = 0; n < 4; ++n) {
        acc[m][n] = __builtin_amdgcn_mfma_f32_16x16x32_fp8_fp8(af[m][0], bb[n][0], acc[m][n], 0, 0, 0);
        acc[m][n] = __builtin_amdgcn_mfma_f32_16x16x32_fp8_fp8(af[m][1], bb[n][1], acc[m][n], 0, 0, 0);
      }
    }
    __builtin_amdgcn_s_setprio(0);
    if (T <= 9)       asm volatile("s_waitcnt vmcnt(4)" ::: "memory");
    else if (T == 10) asm volatile("s_waitcnt vmcnt(0)" ::: "memory");
    __builtin_amdgcn_s_barrier();
  }
#undef STG_A
#undef STG_B

  // ======================= fused-conv epilogue ==============================
  // vmcnt==0 (drained at T=10; T=11 stages nothing) -> smem reusable.
  const float w10 = cw1[0], w11 = cw1[1], w12 = cw1[2], c1b = cb1[0];
  const float w20 = cw2[0], w21 = cw2[1], w22 = cw2[2], c2b = cb2[0];

  u16* fsm = smem;           // fused [c][r]: idx = c*256 + (r ^ ((c&31)<<3))
  u16* tsm = smem + 32768;   // tmp, same layout

  // ---- E1: fused -> LDS bf16 (+ seam store for cols 0-3,124-127) ----
  #pragma unroll
  for (int n = 0; n < 2; ++n) {
    const int cl = wcc * 32 + n * 16 + lo;       // local col 0..127
    const int e  = bx * 128 + cl;
    const float B1 = b1[e], B2 = b2[e];
    #pragma unroll
    for (int m = 0; m < 8; ++m) {
      const int rl = wrr * 128 + m * 16 + hi * 4;
      uint2 pk;
      u16* pku = (u16*)&pk;
      #pragma unroll
      for (int r = 0; r < 4; ++r) {
        const int gr = brow + rl + r;
        const float v1 = acc[m][n][r] * ISCL2 + B1;
        const float v2 = acc[m][n + 2][r] * ISCL2 + B2;
        const float tf = text[(size_t)(gr / Vn) * Dn + e];
        pku[r] = f2bf(fmaxf(tf * v1 + v2, 0.0f));
      }
      *(uint2*)(fsm + cl * 256 + (rl ^ ((cl & 31) << 3))) = pk;
      const int sidx = (cl < 4) ? cl : ((cl >= 124) ? cl - 120 : -1);
      if (sidx >= 0)
        *(uint2*)(seam + ((size_t)(by * 6 + bx) * 8 + sidx) * 256 + rl) = pk;
    }
  }
  __syncthreads();

  // ---- E2: tmp = relu(conv1(fused)), per-thread col; own col kept in regs --
  const int cl = t & 127, rb = t >> 7;
  const int cL = cl ? cl - 1 : 0, cR = (cl < 127) ? cl + 1 : 127;
  short8 tC[8];
  #pragma unroll
  for (int j = 0; j < 8; ++j) {
    const int R = rb * 64 + j * 8;
    short8 sL = *(const short8*)(fsm + cL * 256 + (R ^ ((cL & 31) << 3)));
    short8 sC = *(const short8*)(fsm + cl * 256 + (R ^ ((cl & 31) << 3)));
    short8 sR = *(const short8*)(fsm + cR * 256 + (R ^ ((cR & 31) << 3)));
    short8 o;
    #pragma unroll
    for (int k = 0; k < 8; ++k) {
      float a = bf2f((u16)sL[k]), b = bf2f((u16)sC[k]), c = bf2f((u16)sR[k]);
      float v = fmaxf(fmaf(w10, a, fmaf(w11, b, fmaf(w12, c, c1b))), 0.0f);
      o[k] = (short)f2bf(v);
    }
    *(short8*)(tsm + cl * 256 + (R ^ ((cl & 31) << 3))) = o;
    tC[j] = o;
  }
  __syncthreads();

  // ---- E3: out = conv2(tmp), store interior cols 2..125 ----
  const bool wr_ok = (cl >= 2 && cl <= 125);
  #pragma unroll
  for (int j = 0; j < 8; ++j) {
    const int R = rb * 64 + j * 8;
    short8 tL = *(const short8*)(tsm + cL * 256 + (R ^ ((cL & 31) << 3)));
    short8 tR = *(const short8*)(tsm + cR * 256 + (R ^ ((cR & 31) << 3)));
    #pragma unroll
    for (int k = 0; k < 8; ++k) {
      float v = fmaf(w20, bf2f((u16)tL[k]),
                fmaf(w21, bf2f((u16)tC[j][k]),
                fmaf(w22, bf2f((u16)tR[k]), c2b)));
      if (wr_ok)
        out[(size_t)(brow + R + k) * Dn + bx * 128 + cl] = v;
    }
  }
}

// ------- kernel 4: seam cleanup — out cols {E0,E0+1,E0+126,E0+127} ---------
// Zero-pad semantics: conv2's pad gives tmp(-1)=tmp(768)=0 (NOT conv1 of
// zeros); conv1's pad gives fused(-1)=fused(768)=0 inside tmp(0)/tmp(767).
__global__ __launch_bounds__(256) void seam_k(const u16* __restrict__ seam,
                                              float* __restrict__ out,
                                              const float* __restrict__ cw1,
                                              const float* __restrict__ cb1,
                                              const float* __restrict__ cw2,
                                              const float* __restrict__ cb2) {
  const int bid = blockIdx.x;          // by*6+bx
  const int by = bid / 6, bx = bid - by * 6;
  const int r = threadIdx.x;
  const float w10 = cw1[0], w11 = cw1[1], w12 = cw1[2], c1b = cb1[0];
  const float w20 = cw2[0], w21 = cw2[1], w22 = cw2[2], c2b = cb2[0];
  #define SM(B, I) bf2f(seam[((size_t)(B) * 8 + (I)) * 256 + r])
  float fm2 = 0.f, fm1 = 0.f, fR0 = 0.f, fR1 = 0.f;
  if (bx > 0) { fm2 = SM(bid - 1, 6); fm1 = SM(bid - 1, 7); }
  if (bx < 5) { fR0 = SM(bid + 1, 0); fR1 = SM(bid + 1, 1); }
  const float f0 = SM(bid, 0), f1 = SM(bid, 1), f2 = SM(bid, 2), f3 = SM(bid, 3);
  const float f124 = SM(bid, 4), f125 = SM(bid, 5), f126 = SM(bid, 6), f127 = SM(bid, 7);
  #undef SM
  #define C1(a, b, c) fmaxf(fmaf(w10, (a), fmaf(w11, (b), fmaf(w12, (c), c1b))), 0.0f)
  const float tm1  = (bx > 0) ? C1(fm2, fm1, f0) : 0.0f;   // tmp(-1)=0 at edge
  const float t0   = C1(fm1, f0, f1);
  const float t1   = C1(f0, f1, f2);
  const float t2   = C1(f1, f2, f3);
  const float t125 = C1(f124, f125, f126);
  const float t126 = C1(f125, f126, f127);
  const float t127 = C1(f126, f127, fR0);
  const float t128 = (bx < 5) ? C1(f127, fR0, fR1) : 0.0f;  // tmp(768)=0 at edge
  #undef C1
  const size_t go = (size_t)(by * 256 + r) * Dn + bx * 128;
  out[go + 0]   = fmaf(w20, tm1,  fmaf(w21, t0,   fmaf(w22, t1,   c2b)));
  out[go + 1]   = fmaf(w20, t0,   fmaf(w21, t1,   fmaf(w22, t2,   c2b)));
  out[go + 126] = fmaf(w20, t125, fmaf(w21, t126, fmaf(w22, t127, c2b)));
  out[go + 127] = fmaf(w20, t126, fmaf(w21, t127, fmaf(w22, t128, c2b)));
}

extern "C" void kernel_launch(void* const* d_in, const int* in_sizes, int n_in,
                              void* d_out, int out_size, void* d_ws, size_t ws_size,
                              hipStream_t stream) {
  const float* text = (const float*)d_in[0];
  const float* vf   = (const float*)d_in[1];
  const float* W1   = (const float*)d_in[2];
  const float* b1   = (const float*)d_in[3];
  const float* W2   = (const float*)d_in[4];
  const float* b2   = (const float*)d_in[5];
  const float* cw1  = (const float*)d_in[6];
  const float* cb1  = (const float*)d_in[7];
  const float* cw2  = (const float*)d_in[8];
  const float* cb2  = (const float*)d_in[9];
  float* out = (float*)d_out;

  u8*  X8   = (u8*)d_ws;                                   // [320 panels] tiled fp8 v2
  u8*  Wt8  = X8 + (size_t)Mn * Dn;                        // [6 panels] tiled fp8 v2
  u16* seam = (u16*)(Wt8 + (size_t)Nn * Dn);               // [1920][8][256] bf16

  softmax_k<<<Mn / 32, 512, 0, stream>>>(vf, X8);
  build_wt_k<<<(Dn * (Dn / 4) + 255) / 256, 256, 0, stream>>>(W1, W2, Wt8);
  gemm_fuse_k<<<GRID, 512, 0, stream>>>(X8, Wt8, b1, b2, text, out, seam,
                                        cw1, cb1, cw2, cb2);
  seam_k<<<GRID, 256, 0, stream>>>(seam, out, cw1, cb1, cw2, cb2);
}